// Round 6
// baseline (366.525 us; speedup 1.0000x reference)
//
#include <hip/hip_runtime.h>

typedef __attribute__((ext_vector_type(8))) short bf16x8;
typedef __attribute__((ext_vector_type(4))) float f32x4;

// ---- split-bf16 helpers: value v ~ hi + lo, packed as (hi16<<16)|lo16 ----
__device__ __forceinline__ unsigned bfr16(float x) {            // RNE fp32->bf16 bits
    unsigned u = __float_as_uint(x);
    return (u + 0x7fffu + ((u >> 16) & 1u)) >> 16;
}
__device__ __forceinline__ unsigned pack_bf2(float v) {
    unsigned hr = bfr16(v);
    float lof = v - __uint_as_float(hr << 16);
    unsigned lr = bfr16(lof);
    return (hr << 16) | (lr & 0xffffu);
}
__device__ __forceinline__ float dec_bf2(unsigned p) {
    return __uint_as_float(p & 0xffff0000u) + __uint_as_float(p << 16);
}

union U8 { bf16x8 v; unsigned u[4]; };

// activation B-fragment from 8 consecutive packed u32 (sample = lane&15, k-slice = (lane>>4)*8)
__device__ __forceinline__ void frag_from_packed(const unsigned* ap, bf16x8& hi, bf16x8& lo) {
    uint4 u0 = *(const uint4*)ap;
    uint4 u1 = *(const uint4*)(ap + 4);
    U8 H, L;
    H.u[0] = __builtin_amdgcn_perm(u0.y, u0.x, 0x07060302u);
    H.u[1] = __builtin_amdgcn_perm(u0.w, u0.z, 0x07060302u);
    H.u[2] = __builtin_amdgcn_perm(u1.y, u1.x, 0x07060302u);
    H.u[3] = __builtin_amdgcn_perm(u1.w, u1.z, 0x07060302u);
    L.u[0] = __builtin_amdgcn_perm(u0.y, u0.x, 0x05040100u);
    L.u[1] = __builtin_amdgcn_perm(u0.w, u0.z, 0x05040100u);
    L.u[2] = __builtin_amdgcn_perm(u1.y, u1.x, 0x05040100u);
    L.u[3] = __builtin_amdgcn_perm(u1.w, u1.z, 0x05040100u);
    hi = H.v; lo = L.v;
}

__device__ __forceinline__ void frag_from_f32(const float* fp, bf16x8& hi, bf16x8& lo) {
    float4 f0 = *(const float4*)fp;
    float4 f1 = *(const float4*)(fp + 4);
    float fv[8] = {f0.x, f0.y, f0.z, f0.w, f1.x, f1.y, f1.z, f1.w};
    U8 H, L;
    #pragma unroll
    for (int p = 0; p < 4; p++) {
        float a = fv[2 * p], b = fv[2 * p + 1];
        unsigned ra = bfr16(a), rb = bfr16(b);
        H.u[p] = ra | (rb << 16);
        float la = a - __uint_as_float(ra << 16);
        float lb = b - __uint_as_float(rb << 16);
        L.u[p] = bfr16(la) | (bfr16(lb) << 16);
    }
    hi = H.v; lo = L.v;
}

// weight A-operand fragment pair (hi plane at 0, lo plane at +16384 u16)
__device__ __forceinline__ void wfrag(const unsigned short* Wp, int f, int lane,
                                      bf16x8& whi, bf16x8& wlo) {
    whi = *(const bf16x8*)(Wp + f * 512 + lane * 8);
    wlo = *(const bf16x8*)(Wp + 16384 + f * 512 + lane * 8);
}

#define MFMA3(accv, whi, wlo, yhi, ylo)                                              \
    accv = __builtin_amdgcn_mfma_f32_16x16x32_bf16(whi, yhi, accv, 0, 0, 0);         \
    accv = __builtin_amdgcn_mfma_f32_16x16x32_bf16(whi, ylo, accv, 0, 0, 0);         \
    accv = __builtin_amdgcn_mfma_f32_16x16x32_bf16(wlo, yhi, accv, 0, 0, 0);

// slot->true-channel map: chan(nt, rho=4g+r) = 32*(nt>>1) + 8*g + 4*(nt&1) + r
// self-consistent: B-frag built as acc[2kt+(j>>2)][j&3] reads true channel kt*32+g*8+j.

// layer transition entirely in registers: y(kt) fragment from acc + bias (+relu)
__device__ __forceinline__ void trans_frag(const f32x4* acc, float4 bva, float4 bvb, int kt,
                                           bf16x8& yh, bf16x8& yl) {
    const int n0 = 2 * kt, n1 = n0 + 1;
    float v0 = fmaxf(acc[n0][0] + bva.x, 0.f);
    float v1 = fmaxf(acc[n0][1] + bva.y, 0.f);
    float v2 = fmaxf(acc[n0][2] + bva.z, 0.f);
    float v3 = fmaxf(acc[n0][3] + bva.w, 0.f);
    float v4 = fmaxf(acc[n1][0] + bvb.x, 0.f);
    float v5 = fmaxf(acc[n1][1] + bvb.y, 0.f);
    float v6 = fmaxf(acc[n1][2] + bvb.z, 0.f);
    float v7 = fmaxf(acc[n1][3] + bvb.w, 0.f);
    U8 H, L;
    unsigned ra, rb;
    ra = bfr16(v0); rb = bfr16(v1);
    H.u[0] = ra | (rb << 16);
    L.u[0] = bfr16(v0 - __uint_as_float(ra << 16)) | (bfr16(v1 - __uint_as_float(rb << 16)) << 16);
    ra = bfr16(v2); rb = bfr16(v3);
    H.u[1] = ra | (rb << 16);
    L.u[1] = bfr16(v2 - __uint_as_float(ra << 16)) | (bfr16(v3 - __uint_as_float(rb << 16)) << 16);
    ra = bfr16(v4); rb = bfr16(v5);
    H.u[2] = ra | (rb << 16);
    L.u[2] = bfr16(v4 - __uint_as_float(ra << 16)) | (bfr16(v5 - __uint_as_float(rb << 16)) << 16);
    ra = bfr16(v6); rb = bfr16(v7);
    H.u[3] = ra | (rb << 16);
    L.u[3] = bfr16(v6 - __uint_as_float(ra << 16)) | (bfr16(v7 - __uint_as_float(rb << 16)) << 16);
    yh = H.v; yl = L.v;
}

// ---------------- CSR build ----------------

__global__ void zero2_k(int* __restrict__ a, int* __restrict__ b, int n) {
    int i = blockIdx.x * blockDim.x + threadIdx.x;
    if (i < n) { a[i] = 0; b[i] = 0; }
}

__global__ void hist_k(const int* __restrict__ dst, int* __restrict__ deg, int E) {
    int e = blockIdx.x * blockDim.x + threadIdx.x;
    if (e < E) atomicAdd(&deg[dst[e]], 1);
}

__global__ void scan1_k(const int* __restrict__ deg, int* __restrict__ rowptr,
                        int* __restrict__ bsum, float* __restrict__ dinv, int n) {
    __shared__ int s[256];
    int tid = threadIdx.x;
    int i = blockIdx.x * 256 + tid;
    int v = (i < n) ? deg[i] : 0;
    s[tid] = v;
    __syncthreads();
    #pragma unroll
    for (int off = 1; off < 256; off <<= 1) {
        int t = (tid >= off) ? s[tid - off] : 0;
        __syncthreads();
        s[tid] += t;
        __syncthreads();
    }
    if (i < n) {
        rowptr[i] = s[tid] - v;
        dinv[i] = rsqrtf((float)(v + 1));
    }
    if (tid == 255) bsum[blockIdx.x] = s[255];
}

__global__ void scan2_k(int* __restrict__ bsum, int nb) {
    __shared__ int s[512];
    int tid = threadIdx.x;
    int v = (tid < nb) ? bsum[tid] : 0;
    s[tid] = v;
    __syncthreads();
    #pragma unroll
    for (int off = 1; off < 512; off <<= 1) {
        int t = (tid >= off) ? s[tid - off] : 0;
        __syncthreads();
        s[tid] += t;
        __syncthreads();
    }
    if (tid < nb) bsum[tid] = s[tid] - v;
}

__global__ void scan3_k(int* __restrict__ rowptr, const int* __restrict__ bsum, int n) {
    int i = blockIdx.x * blockDim.x + threadIdx.x;
    if (i < n) rowptr[i] += bsum[i >> 8];
}

__global__ void place_k(const int* __restrict__ src, const int* __restrict__ dst,
                        const int* __restrict__ rowptr, int* __restrict__ cursor,
                        int* __restrict__ csr, int E) {
    int e = blockIdx.x * blockDim.x + threadIdx.x;
    if (e < E) {
        int d = dst[e];
        int pos = rowptr[d] + atomicAdd(&cursor[d], 1);
        csr[pos] = src[e];
    }
}

// ---- weight prep: W[k][c] -> A-operand frag (slot-permuted columns) ----
__global__ void wprep6_k(const float* __restrict__ s0, const float* __restrict__ s1,
                         const float* __restrict__ s2, const float* __restrict__ s3,
                         const float* __restrict__ s4, const float* __restrict__ s5,
                         unsigned short* __restrict__ dstBase) {
    const float* W;
    switch (blockIdx.y) {
        case 0: W = s0; break; case 1: W = s1; break; case 2: W = s2; break;
        case 3: W = s3; break; case 4: W = s4; break; default: W = s5; break;
    }
    unsigned short* out = dstBase + (size_t)blockIdx.y * 32768;
    int idx = blockIdx.x * 256 + threadIdx.x;
    if (idx >= 16384) return;
    int k = idx >> 7, c = idx & 127;
    float v = W[k * 128 + c];
    unsigned hr = bfr16(v);
    float lof = v - __uint_as_float(hr << 16);
    unsigned lr = bfr16(lof);
    int kt = k >> 5, gk = (k >> 3) & 3, j = k & 7;
    int nt = ((c >> 5) << 1) | ((c >> 2) & 1);
    int rho = (((c >> 3) & 3) << 2) | (c & 3);
    int lane = (gk << 4) | rho;
    int pos = (kt * 8 + nt) * 512 + lane * 8 + j;
    out[pos] = (unsigned short)hr;
    out[16384 + pos] = (unsigned short)lr;
}

// ---- gather aggregate: out[i] = relu(bias + dinv[i]*(hp[i] + sum_in hp[s])), packed.
// 4 nodes per wave (16 lanes x 8 channels each); 4-way unrolled neighbor loop.
__global__ __launch_bounds__(256)
void gather4_k(const unsigned* __restrict__ hp, const float* __restrict__ dinv,
               const int* __restrict__ rowptr, const int* __restrict__ deg,
               const int* __restrict__ csr, const float* __restrict__ bias,
               unsigned* __restrict__ out, int N)
{
    int tid = threadIdx.x;
    int lane = tid & 63;
    int grp = lane >> 4, cl = lane & 15;
    int i = blockIdx.x * 16 + (tid >> 6) * 4 + grp;
    if (i >= N) return;
    int c8 = cl * 8;
    const unsigned* row = hp + (size_t)i * 128 + c8;
    uint4 p0 = *(const uint4*)row;
    uint4 p1 = *(const uint4*)(row + 4);
    float a0 = dec_bf2(p0.x), a1 = dec_bf2(p0.y), a2 = dec_bf2(p0.z), a3 = dec_bf2(p0.w);
    float a4 = dec_bf2(p1.x), a5 = dec_bf2(p1.y), a6 = dec_bf2(p1.z), a7 = dec_bf2(p1.w);
    int beg = rowptr[i], dg = deg[i];
    int j = 0;
    for (; j + 3 < dg; j += 4) {
        int s0 = csr[beg + j],     s1 = csr[beg + j + 1];
        int s2 = csr[beg + j + 2], s3 = csr[beg + j + 3];
        const unsigned* r0 = hp + (size_t)s0 * 128 + c8;
        const unsigned* r1 = hp + (size_t)s1 * 128 + c8;
        const unsigned* r2 = hp + (size_t)s2 * 128 + c8;
        const unsigned* r3 = hp + (size_t)s3 * 128 + c8;
        uint4 q00 = *(const uint4*)r0, q01 = *(const uint4*)(r0 + 4);
        uint4 q10 = *(const uint4*)r1, q11 = *(const uint4*)(r1 + 4);
        uint4 q20 = *(const uint4*)r2, q21 = *(const uint4*)(r2 + 4);
        uint4 q30 = *(const uint4*)r3, q31 = *(const uint4*)(r3 + 4);
        a0 += (dec_bf2(q00.x) + dec_bf2(q10.x)) + (dec_bf2(q20.x) + dec_bf2(q30.x));
        a1 += (dec_bf2(q00.y) + dec_bf2(q10.y)) + (dec_bf2(q20.y) + dec_bf2(q30.y));
        a2 += (dec_bf2(q00.z) + dec_bf2(q10.z)) + (dec_bf2(q20.z) + dec_bf2(q30.z));
        a3 += (dec_bf2(q00.w) + dec_bf2(q10.w)) + (dec_bf2(q20.w) + dec_bf2(q30.w));
        a4 += (dec_bf2(q01.x) + dec_bf2(q11.x)) + (dec_bf2(q21.x) + dec_bf2(q31.x));
        a5 += (dec_bf2(q01.y) + dec_bf2(q11.y)) + (dec_bf2(q21.y) + dec_bf2(q31.y));
        a6 += (dec_bf2(q01.z) + dec_bf2(q11.z)) + (dec_bf2(q21.z) + dec_bf2(q31.z));
        a7 += (dec_bf2(q01.w) + dec_bf2(q11.w)) + (dec_bf2(q21.w) + dec_bf2(q31.w));
    }
    for (; j < dg; j++) {
        int s0 = csr[beg + j];
        const unsigned* r0 = hp + (size_t)s0 * 128 + c8;
        uint4 q0 = *(const uint4*)r0, q1 = *(const uint4*)(r0 + 4);
        a0 += dec_bf2(q0.x); a1 += dec_bf2(q0.y); a2 += dec_bf2(q0.z); a3 += dec_bf2(q0.w);
        a4 += dec_bf2(q1.x); a5 += dec_bf2(q1.y); a6 += dec_bf2(q1.z); a7 += dec_bf2(q1.w);
    }
    float di = dinv[i];
    float4 bv0 = *(const float4*)(bias + c8);
    float4 bv1 = *(const float4*)(bias + c8 + 4);
    uint4 o0, o1;
    o0.x = pack_bf2(fmaxf(bv0.x + di * a0, 0.f));
    o0.y = pack_bf2(fmaxf(bv0.y + di * a1, 0.f));
    o0.z = pack_bf2(fmaxf(bv0.z + di * a2, 0.f));
    o0.w = pack_bf2(fmaxf(bv0.w + di * a3, 0.f));
    o1.x = pack_bf2(fmaxf(bv1.x + di * a4, 0.f));
    o1.y = pack_bf2(fmaxf(bv1.y + di * a5, 0.f));
    o1.z = pack_bf2(fmaxf(bv1.z + di * a6, 0.f));
    o1.w = pack_bf2(fmaxf(bv1.w + di * a7, 0.f));
    *(uint4*)(out + (size_t)i * 128 + c8) = o0;
    *(uint4*)(out + (size_t)i * 128 + c8 + 4) = o1;
}

// ---- layer GEMM: C = dinv-row-scaled (A @ W), packed out. 2 sample-sets per wave (32 rows).
template<int AMODE>   // 0: A fp32 ; 1: A packed split-bf16
__global__ __launch_bounds__(512)
void rowgemm_k(const void* __restrict__ Asrc, const unsigned short* __restrict__ Wp,
               const float* __restrict__ rowScale, unsigned* __restrict__ Cout, int M)
{
    const int t = threadIdx.x, lane = t & 63, wave = t >> 6;
    const int base = blockIdx.x * 256 + wave * 32;
    const int s = lane & 15, g = lane >> 4, kg = g * 8;
    const int r0 = base + s, r1 = base + 16 + s;
    const int rc0 = (r0 < M) ? r0 : (M - 1);
    const int rc1 = (r1 < M) ? r1 : (M - 1);

    f32x4 acc[2][8];
    #pragma unroll
    for (int st = 0; st < 2; st++)
        #pragma unroll
        for (int nt = 0; nt < 8; nt++) acc[st][nt] = (f32x4){0.f, 0.f, 0.f, 0.f};

    #pragma unroll
    for (int kt = 0; kt < 4; kt++) {
        bf16x8 y0h, y0l, y1h, y1l;
        if (AMODE == 1) {
            frag_from_packed((const unsigned*)Asrc + (size_t)rc0 * 128 + kt * 32 + kg, y0h, y0l);
            frag_from_packed((const unsigned*)Asrc + (size_t)rc1 * 128 + kt * 32 + kg, y1h, y1l);
        } else {
            frag_from_f32((const float*)Asrc + (size_t)rc0 * 128 + kt * 32 + kg, y0h, y0l);
            frag_from_f32((const float*)Asrc + (size_t)rc1 * 128 + kt * 32 + kg, y1h, y1l);
        }
        #pragma unroll
        for (int nt = 0; nt < 8; nt++) {
            bf16x8 whi, wlo;
            wfrag(Wp, kt * 8 + nt, lane, whi, wlo);
            MFMA3(acc[0][nt], whi, wlo, y0h, y0l);
            MFMA3(acc[1][nt], whi, wlo, y1h, y1l);
        }
    }

    #pragma unroll
    for (int st = 0; st < 2; st++) {
        int arow = st ? r1 : r0;
        if (arow < M) {
            float sc = rowScale[arow];
            #pragma unroll
            for (int nt = 0; nt < 8; nt++) {
                int cbase = 32 * (nt >> 1) + 8 * g + 4 * (nt & 1);
                uint4 o;
                o.x = pack_bf2(acc[st][nt][0] * sc);
                o.y = pack_bf2(acc[st][nt][1] * sc);
                o.z = pack_bf2(acc[st][nt][2] * sc);
                o.w = pack_bf2(acc[st][nt][3] * sc);
                *(uint4*)(Cout + (size_t)arow * 128 + cbase) = o;
            }
        }
    }
}

// ---- fused predict MLP: gather xi/xj -> y1 -> y2 -> y3 -> dot -> out. Zero LDS.
// 2 sample-sets per wave (32 rows), weight fragments reused across both sets.
__global__ __launch_bounds__(512)
void mlp_k(const unsigned* __restrict__ X, const int* __restrict__ psrc, const int* __restrict__ pdst,
           const unsigned short* __restrict__ W1a, const unsigned short* __restrict__ W1b,
           const float* __restrict__ b1, const unsigned short* __restrict__ W2p,
           const float* __restrict__ b2, const unsigned short* __restrict__ W3p,
           const float* __restrict__ b3, const float* __restrict__ w4,
           const float* __restrict__ b4p, float* __restrict__ out, int M)
{
    const int t = threadIdx.x, lane = t & 63, wave = t >> 6;
    const int base = blockIdx.x * 256 + wave * 32;
    const int s = lane & 15, g = lane >> 4, kg = g * 8;
    const int r0 = base + s, r1 = base + 16 + s;
    const int rc0 = (r0 < M) ? r0 : (M - 1);
    const int rc1 = (r1 < M) ? r1 : (M - 1);
    const int si0 = psrc[rc0], sj0 = pdst[rc0];
    const int si1 = psrc[rc1], sj1 = pdst[rc1];

    // ---- layer 1: acc1[st] = W1a^T·xi[st] + W1b^T·xj[st] ----
    f32x4 acc1[2][8];
    #pragma unroll
    for (int st = 0; st < 2; st++)
        #pragma unroll
        for (int nt = 0; nt < 8; nt++) acc1[st][nt] = (f32x4){0.f, 0.f, 0.f, 0.f};
    #pragma unroll
    for (int kt = 0; kt < 4; kt++) {
        bf16x8 xi0h, xi0l, xj0h, xj0l, xi1h, xi1l, xj1h, xj1l;
        frag_from_packed(X + (size_t)si0 * 128 + kt * 32 + kg, xi0h, xi0l);
        frag_from_packed(X + (size_t)sj0 * 128 + kt * 32 + kg, xj0h, xj0l);
        frag_from_packed(X + (size_t)si1 * 128 + kt * 32 + kg, xi1h, xi1l);
        frag_from_packed(X + (size_t)sj1 * 128 + kt * 32 + kg, xj1h, xj1l);
        #pragma unroll
        for (int nt = 0; nt < 8; nt++) {
            bf16x8 whi, wlo;
            wfrag(W1a, kt * 8 + nt, lane, whi, wlo);
            MFMA3(acc1[0][nt], whi, wlo, xi0h, xi0l);
            MFMA3(acc1[1][nt], whi, wlo, xi1h, xi1l);
            wfrag(W1b, kt * 8 + nt, lane, whi, wlo);
            MFMA3(acc1[0][nt], whi, wlo, xj0h, xj0l);
            MFMA3(acc1[1][nt], whi, wlo, xj1h, xj1l);
        }
    }
    __syncthreads();   // keep waves in lockstep for L1 weight reuse

    // ---- layer 2 ----
    f32x4 acc2[2][8];
    #pragma unroll
    for (int st = 0; st < 2; st++)
        #pragma unroll
        for (int nt = 0; nt < 8; nt++) acc2[st][nt] = (f32x4){0.f, 0.f, 0.f, 0.f};
    #pragma unroll
    for (int kt = 0; kt < 4; kt++) {
        float4 bva = *(const float4*)(b1 + 32 * kt + 8 * g);
        float4 bvb = *(const float4*)(b1 + 32 * kt + 8 * g + 4);
        bf16x8 y0h, y0l, y1h, y1l;
        trans_frag(acc1[0], bva, bvb, kt, y0h, y0l);
        trans_frag(acc1[1], bva, bvb, kt, y1h, y1l);
        #pragma unroll
        for (int nt = 0; nt < 8; nt++) {
            bf16x8 whi, wlo;
            wfrag(W2p, kt * 8 + nt, lane, whi, wlo);
            MFMA3(acc2[0][nt], whi, wlo, y0h, y0l);
            MFMA3(acc2[1][nt], whi, wlo, y1h, y1l);
        }
    }
    __syncthreads();

    // ---- layer 3 ----
    f32x4 acc3[2][8];
    #pragma unroll
    for (int st = 0; st < 2; st++)
        #pragma unroll
        for (int nt = 0; nt < 8; nt++) acc3[st][nt] = (f32x4){0.f, 0.f, 0.f, 0.f};
    #pragma unroll
    for (int kt = 0; kt < 4; kt++) {
        float4 bva = *(const float4*)(b2 + 32 * kt + 8 * g);
        float4 bvb = *(const float4*)(b2 + 32 * kt + 8 * g + 4);
        bf16x8 y0h, y0l, y1h, y1l;
        trans_frag(acc2[0], bva, bvb, kt, y0h, y0l);
        trans_frag(acc2[1], bva, bvb, kt, y1h, y1l);
        #pragma unroll
        for (int nt = 0; nt < 8; nt++) {
            bf16x8 whi, wlo;
            wfrag(W3p, kt * 8 + nt, lane, whi, wlo);
            MFMA3(acc3[0][nt], whi, wlo, y0h, y0l);
            MFMA3(acc3[1][nt], whi, wlo, y1h, y1l);
        }
    }

    // ---- final: out = relu( sum_c relu(y3[c]) * w4[c] + b4 ) ----
    float p0 = 0.f, p1 = 0.f;
    #pragma unroll
    for (int nt = 0; nt < 8; nt++) {
        int off = 32 * (nt >> 1) + 8 * g + 4 * (nt & 1);
        float4 b3v = *(const float4*)(b3 + off);
        float4 w4v = *(const float4*)(w4 + off);
        p0 += fmaxf(acc3[0][nt][0] + b3v.x, 0.f) * w4v.x;
        p0 += fmaxf(acc3[0][nt][1] + b3v.y, 0.f) * w4v.y;
        p0 += fmaxf(acc3[0][nt][2] + b3v.z, 0.f) * w4v.z;
        p0 += fmaxf(acc3[0][nt][3] + b3v.w, 0.f) * w4v.w;
        p1 += fmaxf(acc3[1][nt][0] + b3v.x, 0.f) * w4v.x;
        p1 += fmaxf(acc3[1][nt][1] + b3v.y, 0.f) * w4v.y;
        p1 += fmaxf(acc3[1][nt][2] + b3v.z, 0.f) * w4v.z;
        p1 += fmaxf(acc3[1][nt][3] + b3v.w, 0.f) * w4v.w;
    }
    p0 += __shfl_xor(p0, 16, 64);
    p0 += __shfl_xor(p0, 32, 64);
    p1 += __shfl_xor(p1, 16, 64);
    p1 += __shfl_xor(p1, 32, 64);
    if (g == 0) {
        float bb = b4p[0];
        if (r0 < M) out[r0] = fmaxf(p0 + bb, 0.f);
        if (r1 < M) out[r1] = fmaxf(p1 + bb, 0.f);
    }
}

extern "C" void kernel_launch(void* const* d_in, const int* in_sizes, int n_in,
                              void* d_out, int out_size, void* d_ws, size_t ws_size,
                              hipStream_t stream)
{
    const float* x   = (const float*)d_in[0];
    const int*   ei  = (const int*)d_in[2];
    const int*   pei = (const int*)d_in[3];
    const float* W1  = (const float*)d_in[4];
    const float* b1  = (const float*)d_in[5];
    const float* W2  = (const float*)d_in[6];
    const float* b2  = (const float*)d_in[7];
    // d_in[8..11] = edge_mlp weights: dead w.r.t. output, skipped
    const float* pW1 = (const float*)d_in[12];
    const float* pb1 = (const float*)d_in[13];
    const float* pW2 = (const float*)d_in[14];
    const float* pb2 = (const float*)d_in[15];
    const float* pW3 = (const float*)d_in[16];
    const float* pb3 = (const float*)d_in[17];
    const float* pW4 = (const float*)d_in[18];
    const float* pb4 = (const float*)d_in[19];

    const int N  = in_sizes[0] / 128;
    const int E  = in_sizes[2] / 2;
    const int EP = in_sizes[3] / 2;
    const int Npad = (N + 255) & ~255;

    float*    ws     = (float*)d_ws;
    float*    dinv   = ws;                                  // Npad
    unsigned* bufA   = (unsigned*)(ws + Npad);              // N*128
    unsigned* bufB   = bufA + (size_t)N * 128;              // N*128
    int*      deg    = (int*)(bufB + (size_t)N * 128);      // Npad
    int*      rowptr = deg + Npad;                          // Npad
    int*      cursor = rowptr + Npad;                       // Npad
    int*      csr    = cursor + Npad;                       // E
    int*      bsum   = csr + E;                             // 512
    size_t wpOff = ((size_t)(bsum + 512) + 15) & ~(size_t)15;
    unsigned short* wp = (unsigned short*)wpOff;            // 6 x 32768 u16
    unsigned short* W1p  = wp;
    unsigned short* W2p  = wp + 32768;
    unsigned short* P1Ap = wp + 2 * 32768;
    unsigned short* P1Bp = wp + 3 * 32768;
    unsigned short* P2p  = wp + 4 * 32768;
    unsigned short* P3p  = wp + 5 * 32768;
    float* out = (float*)d_out;

    const int* esrc = ei;
    const int* edst = ei + E;
    const int* psrc = pei;
    const int* pdst = pei + EP;

    const int nb = (N + 255) / 256;
    const int gN = (N + 255) / 256;
    const int gE = (E + 255) / 256;
    const int gT = (N + 255) / 256;     // 256 rows per block now
    const int gP = (EP + 255) / 256;
    const int gG = (N + 15) / 16;

    // ---- CSR build + dinv ----
    zero2_k<<<gN, 256, 0, stream>>>(deg, cursor, N);
    hist_k<<<gE, 256, 0, stream>>>(edst, deg, E);
    scan1_k<<<nb, 256, 0, stream>>>(deg, rowptr, bsum, dinv, N);
    scan2_k<<<1, 512, 0, stream>>>(bsum, nb);
    scan3_k<<<gN, 256, 0, stream>>>(rowptr, bsum, N);
    place_k<<<gE, 256, 0, stream>>>(esrc, edst, rowptr, cursor, csr, E);

    // ---- weight prep ----
    wprep6_k<<<dim3(64, 6), 256, 0, stream>>>(W1, W2, pW1, pW1 + 128 * 128, pW2, pW3, wp);

    // ---- layer 0: hp1 = dinv ⊙ (x@W1); x1r = relu(agg + b1) ----
    rowgemm_k<0><<<gT, 512, 0, stream>>>(x, W1p, dinv, bufA, N);
    gather4_k<<<gG, 256, 0, stream>>>(bufA, dinv, rowptr, deg, csr, b1, bufB, N);

    // ---- layer 1 ----
    rowgemm_k<1><<<gT, 512, 0, stream>>>(bufB, W2p, dinv, bufA, N);
    gather4_k<<<gG, 256, 0, stream>>>(bufA, dinv, rowptr, deg, csr, b2, bufB, N);

    // ---- fused predict MLP ----
    mlp_k<<<gP, 512, 0, stream>>>(bufB, psrc, pdst, P1Ap, P1Bp, pb1, P2p, pb2, P3p, pb3,
                                  pW4, pb4, out, EP);
}

// Round 7
// 301.716 us; speedup vs baseline: 1.2148x; 1.2148x over previous
//
#include <hip/hip_runtime.h>

typedef __attribute__((ext_vector_type(8))) short bf16x8;
typedef __attribute__((ext_vector_type(4))) float f32x4;

// ---- split-bf16 helpers: value v ~ hi + lo, packed as (hi16<<16)|lo16 ----
__device__ __forceinline__ unsigned bfr16(float x) {            // RNE fp32->bf16 bits
    unsigned u = __float_as_uint(x);
    return (u + 0x7fffu + ((u >> 16) & 1u)) >> 16;
}
__device__ __forceinline__ unsigned pack_bf2(float v) {
    unsigned hr = bfr16(v);
    float lof = v - __uint_as_float(hr << 16);
    unsigned lr = bfr16(lof);
    return (hr << 16) | (lr & 0xffffu);
}
__device__ __forceinline__ float dec_bf2(unsigned p) {
    return __uint_as_float(p & 0xffff0000u) + __uint_as_float(p << 16);
}

union U8 { bf16x8 v; unsigned u[4]; };

// activation B-fragment from 8 consecutive packed u32 (sample = lane&15, k-slice = (lane>>4)*8)
__device__ __forceinline__ void frag_from_packed(const unsigned* ap, bf16x8& hi, bf16x8& lo) {
    uint4 u0 = *(const uint4*)ap;
    uint4 u1 = *(const uint4*)(ap + 4);
    U8 H, L;
    H.u[0] = __builtin_amdgcn_perm(u0.y, u0.x, 0x07060302u);
    H.u[1] = __builtin_amdgcn_perm(u0.w, u0.z, 0x07060302u);
    H.u[2] = __builtin_amdgcn_perm(u1.y, u1.x, 0x07060302u);
    H.u[3] = __builtin_amdgcn_perm(u1.w, u1.z, 0x07060302u);
    L.u[0] = __builtin_amdgcn_perm(u0.y, u0.x, 0x05040100u);
    L.u[1] = __builtin_amdgcn_perm(u0.w, u0.z, 0x05040100u);
    L.u[2] = __builtin_amdgcn_perm(u1.y, u1.x, 0x05040100u);
    L.u[3] = __builtin_amdgcn_perm(u1.w, u1.z, 0x05040100u);
    hi = H.v; lo = L.v;
}

__device__ __forceinline__ void frag_from_f32(const float* fp, bf16x8& hi, bf16x8& lo) {
    float4 f0 = *(const float4*)fp;
    float4 f1 = *(const float4*)(fp + 4);
    float fv[8] = {f0.x, f0.y, f0.z, f0.w, f1.x, f1.y, f1.z, f1.w};
    U8 H, L;
    #pragma unroll
    for (int p = 0; p < 4; p++) {
        float a = fv[2 * p], b = fv[2 * p + 1];
        unsigned ra = bfr16(a), rb = bfr16(b);
        H.u[p] = ra | (rb << 16);
        float la = a - __uint_as_float(ra << 16);
        float lb = b - __uint_as_float(rb << 16);
        L.u[p] = bfr16(la) | (bfr16(lb) << 16);
    }
    hi = H.v; lo = L.v;
}

// stage one prepped weight matrix (64 KB: hi plane 32 KB + lo plane 32 KB) into LDS
__device__ __forceinline__ void stage_w(unsigned short* sm, const unsigned short* Wp, int t) {
    const uint4* src = (const uint4*)Wp;
    uint4* dst = (uint4*)sm;
    #pragma unroll
    for (int p = 0; p < 8; p++) dst[t + p * 512] = src[t + p * 512];
}

// weight A-operand fragment pair from LDS (hi at 0, lo at +16384 u16)
__device__ __forceinline__ void wfrag_lds(const unsigned short* sm, int f, int lane,
                                          bf16x8& whi, bf16x8& wlo) {
    whi = *(const bf16x8*)(sm + f * 512 + lane * 8);
    wlo = *(const bf16x8*)(sm + 16384 + f * 512 + lane * 8);
}

#define MFMA3(accv, whi, wlo, yhi, ylo)                                              \
    accv = __builtin_amdgcn_mfma_f32_16x16x32_bf16(whi, yhi, accv, 0, 0, 0);         \
    accv = __builtin_amdgcn_mfma_f32_16x16x32_bf16(whi, ylo, accv, 0, 0, 0);         \
    accv = __builtin_amdgcn_mfma_f32_16x16x32_bf16(wlo, yhi, accv, 0, 0, 0);

// slot->true-channel map: chan(nt, rho=4g+r) = 32*(nt>>1) + 8*g + 4*(nt&1) + r
// self-consistent: B-frag built as acc[2kt+(j>>2)][j&3] reads true channel kt*32+g*8+j.

// layer transition entirely in registers: y(kt) fragment from acc + bias (+relu)
__device__ __forceinline__ void trans_frag(const f32x4* acc, float4 bva, float4 bvb, int kt,
                                           bf16x8& yh, bf16x8& yl) {
    const int n0 = 2 * kt, n1 = n0 + 1;
    float v0 = fmaxf(acc[n0][0] + bva.x, 0.f);
    float v1 = fmaxf(acc[n0][1] + bva.y, 0.f);
    float v2 = fmaxf(acc[n0][2] + bva.z, 0.f);
    float v3 = fmaxf(acc[n0][3] + bva.w, 0.f);
    float v4 = fmaxf(acc[n1][0] + bvb.x, 0.f);
    float v5 = fmaxf(acc[n1][1] + bvb.y, 0.f);
    float v6 = fmaxf(acc[n1][2] + bvb.z, 0.f);
    float v7 = fmaxf(acc[n1][3] + bvb.w, 0.f);
    U8 H, L;
    unsigned ra, rb;
    ra = bfr16(v0); rb = bfr16(v1);
    H.u[0] = ra | (rb << 16);
    L.u[0] = bfr16(v0 - __uint_as_float(ra << 16)) | (bfr16(v1 - __uint_as_float(rb << 16)) << 16);
    ra = bfr16(v2); rb = bfr16(v3);
    H.u[1] = ra | (rb << 16);
    L.u[1] = bfr16(v2 - __uint_as_float(ra << 16)) | (bfr16(v3 - __uint_as_float(rb << 16)) << 16);
    ra = bfr16(v4); rb = bfr16(v5);
    H.u[2] = ra | (rb << 16);
    L.u[2] = bfr16(v4 - __uint_as_float(ra << 16)) | (bfr16(v5 - __uint_as_float(rb << 16)) << 16);
    ra = bfr16(v6); rb = bfr16(v7);
    H.u[3] = ra | (rb << 16);
    L.u[3] = bfr16(v6 - __uint_as_float(ra << 16)) | (bfr16(v7 - __uint_as_float(rb << 16)) << 16);
    yh = H.v; yl = L.v;
}

// ---------------- CSR build ----------------

__global__ void zero2_k(int* __restrict__ a, int* __restrict__ b, int n) {
    int i = blockIdx.x * blockDim.x + threadIdx.x;
    if (i < n) { a[i] = 0; b[i] = 0; }
}

__global__ void hist_k(const int* __restrict__ dst, int* __restrict__ deg, int E) {
    int e = blockIdx.x * blockDim.x + threadIdx.x;
    if (e < E) atomicAdd(&deg[dst[e]], 1);
}

__global__ void scan1_k(const int* __restrict__ deg, int* __restrict__ rowptr,
                        int* __restrict__ bsum, float* __restrict__ dinv, int n) {
    __shared__ int s[256];
    int tid = threadIdx.x;
    int i = blockIdx.x * 256 + tid;
    int v = (i < n) ? deg[i] : 0;
    s[tid] = v;
    __syncthreads();
    #pragma unroll
    for (int off = 1; off < 256; off <<= 1) {
        int t = (tid >= off) ? s[tid - off] : 0;
        __syncthreads();
        s[tid] += t;
        __syncthreads();
    }
    if (i < n) {
        rowptr[i] = s[tid] - v;
        dinv[i] = rsqrtf((float)(v + 1));
    }
    if (tid == 255) bsum[blockIdx.x] = s[255];
}

__global__ void scan2_k(int* __restrict__ bsum, int nb) {
    __shared__ int s[512];
    int tid = threadIdx.x;
    int v = (tid < nb) ? bsum[tid] : 0;
    s[tid] = v;
    __syncthreads();
    #pragma unroll
    for (int off = 1; off < 512; off <<= 1) {
        int t = (tid >= off) ? s[tid - off] : 0;
        __syncthreads();
        s[tid] += t;
        __syncthreads();
    }
    if (tid < nb) bsum[tid] = s[tid] - v;
}

__global__ void scan3_k(int* __restrict__ rowptr, const int* __restrict__ bsum, int n) {
    int i = blockIdx.x * blockDim.x + threadIdx.x;
    if (i < n) rowptr[i] += bsum[i >> 8];
}

__global__ void place_k(const int* __restrict__ src, const int* __restrict__ dst,
                        const int* __restrict__ rowptr, int* __restrict__ cursor,
                        int* __restrict__ csr, int E) {
    int e = blockIdx.x * blockDim.x + threadIdx.x;
    if (e < E) {
        int d = dst[e];
        int pos = rowptr[d] + atomicAdd(&cursor[d], 1);
        csr[pos] = src[e];
    }
}

// ---- weight prep: W[k][c] -> A-operand frag (slot-permuted columns) ----
__global__ void wprep6_k(const float* __restrict__ s0, const float* __restrict__ s1,
                         const float* __restrict__ s2, const float* __restrict__ s3,
                         const float* __restrict__ s4, const float* __restrict__ s5,
                         unsigned short* __restrict__ dstBase) {
    const float* W;
    switch (blockIdx.y) {
        case 0: W = s0; break; case 1: W = s1; break; case 2: W = s2; break;
        case 3: W = s3; break; case 4: W = s4; break; default: W = s5; break;
    }
    unsigned short* out = dstBase + (size_t)blockIdx.y * 32768;
    int idx = blockIdx.x * 256 + threadIdx.x;
    if (idx >= 16384) return;
    int k = idx >> 7, c = idx & 127;
    float v = W[k * 128 + c];
    unsigned hr = bfr16(v);
    float lof = v - __uint_as_float(hr << 16);
    unsigned lr = bfr16(lof);
    int kt = k >> 5, gk = (k >> 3) & 3, j = k & 7;
    int nt = ((c >> 5) << 1) | ((c >> 2) & 1);
    int rho = (((c >> 3) & 3) << 2) | (c & 3);
    int lane = (gk << 4) | rho;
    int pos = (kt * 8 + nt) * 512 + lane * 8 + j;
    out[pos] = (unsigned short)hr;
    out[16384 + pos] = (unsigned short)lr;
}

// ---- gather aggregate: out[i] = relu(bias + dinv[i]*(hp[i] + sum_in hp[s])), packed.
// 4 nodes per wave (16 lanes x 8 channels each); 4-way unrolled neighbor loop.
__global__ __launch_bounds__(256)
void gather4_k(const unsigned* __restrict__ hp, const float* __restrict__ dinv,
               const int* __restrict__ rowptr, const int* __restrict__ deg,
               const int* __restrict__ csr, const float* __restrict__ bias,
               unsigned* __restrict__ out, int N)
{
    int tid = threadIdx.x;
    int lane = tid & 63;
    int grp = lane >> 4, cl = lane & 15;
    int i = blockIdx.x * 16 + (tid >> 6) * 4 + grp;
    if (i >= N) return;
    int c8 = cl * 8;
    const unsigned* row = hp + (size_t)i * 128 + c8;
    uint4 p0 = *(const uint4*)row;
    uint4 p1 = *(const uint4*)(row + 4);
    float a0 = dec_bf2(p0.x), a1 = dec_bf2(p0.y), a2 = dec_bf2(p0.z), a3 = dec_bf2(p0.w);
    float a4 = dec_bf2(p1.x), a5 = dec_bf2(p1.y), a6 = dec_bf2(p1.z), a7 = dec_bf2(p1.w);
    int beg = rowptr[i], dg = deg[i];
    int j = 0;
    for (; j + 3 < dg; j += 4) {
        int s0 = csr[beg + j],     s1 = csr[beg + j + 1];
        int s2 = csr[beg + j + 2], s3 = csr[beg + j + 3];
        const unsigned* r0 = hp + (size_t)s0 * 128 + c8;
        const unsigned* r1 = hp + (size_t)s1 * 128 + c8;
        const unsigned* r2 = hp + (size_t)s2 * 128 + c8;
        const unsigned* r3 = hp + (size_t)s3 * 128 + c8;
        uint4 q00 = *(const uint4*)r0, q01 = *(const uint4*)(r0 + 4);
        uint4 q10 = *(const uint4*)r1, q11 = *(const uint4*)(r1 + 4);
        uint4 q20 = *(const uint4*)r2, q21 = *(const uint4*)(r2 + 4);
        uint4 q30 = *(const uint4*)r3, q31 = *(const uint4*)(r3 + 4);
        a0 += (dec_bf2(q00.x) + dec_bf2(q10.x)) + (dec_bf2(q20.x) + dec_bf2(q30.x));
        a1 += (dec_bf2(q00.y) + dec_bf2(q10.y)) + (dec_bf2(q20.y) + dec_bf2(q30.y));
        a2 += (dec_bf2(q00.z) + dec_bf2(q10.z)) + (dec_bf2(q20.z) + dec_bf2(q30.z));
        a3 += (dec_bf2(q00.w) + dec_bf2(q10.w)) + (dec_bf2(q20.w) + dec_bf2(q30.w));
        a4 += (dec_bf2(q01.x) + dec_bf2(q11.x)) + (dec_bf2(q21.x) + dec_bf2(q31.x));
        a5 += (dec_bf2(q01.y) + dec_bf2(q11.y)) + (dec_bf2(q21.y) + dec_bf2(q31.y));
        a6 += (dec_bf2(q01.z) + dec_bf2(q11.z)) + (dec_bf2(q21.z) + dec_bf2(q31.z));
        a7 += (dec_bf2(q01.w) + dec_bf2(q11.w)) + (dec_bf2(q21.w) + dec_bf2(q31.w));
    }
    for (; j < dg; j++) {
        int s0 = csr[beg + j];
        const unsigned* r0 = hp + (size_t)s0 * 128 + c8;
        uint4 q0 = *(const uint4*)r0, q1 = *(const uint4*)(r0 + 4);
        a0 += dec_bf2(q0.x); a1 += dec_bf2(q0.y); a2 += dec_bf2(q0.z); a3 += dec_bf2(q0.w);
        a4 += dec_bf2(q1.x); a5 += dec_bf2(q1.y); a6 += dec_bf2(q1.z); a7 += dec_bf2(q1.w);
    }
    float di = dinv[i];
    float4 bv0 = *(const float4*)(bias + c8);
    float4 bv1 = *(const float4*)(bias + c8 + 4);
    uint4 o0, o1;
    o0.x = pack_bf2(fmaxf(bv0.x + di * a0, 0.f));
    o0.y = pack_bf2(fmaxf(bv0.y + di * a1, 0.f));
    o0.z = pack_bf2(fmaxf(bv0.z + di * a2, 0.f));
    o0.w = pack_bf2(fmaxf(bv0.w + di * a3, 0.f));
    o1.x = pack_bf2(fmaxf(bv1.x + di * a4, 0.f));
    o1.y = pack_bf2(fmaxf(bv1.y + di * a5, 0.f));
    o1.z = pack_bf2(fmaxf(bv1.z + di * a6, 0.f));
    o1.w = pack_bf2(fmaxf(bv1.w + di * a7, 0.f));
    *(uint4*)(out + (size_t)i * 128 + c8) = o0;
    *(uint4*)(out + (size_t)i * 128 + c8 + 4) = o1;
}

// ---- layer GEMM: C = dinv-row-scaled (A @ W), packed out. 16 rows/wave, W in LDS. ----
template<int AMODE>   // 0: A fp32 ; 1: A packed split-bf16
__global__ __launch_bounds__(512)
void rowgemm_k(const void* __restrict__ Asrc, const unsigned short* __restrict__ Wp,
               const float* __restrict__ rowScale, unsigned* __restrict__ Cout, int M)
{
    __shared__ __align__(16) unsigned short smw[32768];   // 64 KB: one prepped weight matrix
    const int t = threadIdx.x, lane = t & 63, wave = t >> 6;
    const int base = blockIdx.x * 128 + wave * 16;
    const int s = lane & 15, g = lane >> 4, kg = g * 8;
    const int arow = base + s;
    const int rowc = (arow < M) ? arow : (M - 1);

    stage_w(smw, Wp, t);

    // load A fragments while the staging lands
    bf16x8 yh[4], yl[4];
    #pragma unroll
    for (int kt = 0; kt < 4; kt++) {
        if (AMODE == 1)
            frag_from_packed((const unsigned*)Asrc + (size_t)rowc * 128 + kt * 32 + kg, yh[kt], yl[kt]);
        else
            frag_from_f32((const float*)Asrc + (size_t)rowc * 128 + kt * 32 + kg, yh[kt], yl[kt]);
    }
    __syncthreads();

    f32x4 acc[8];
    #pragma unroll
    for (int nt = 0; nt < 8; nt++) acc[nt] = (f32x4){0.f, 0.f, 0.f, 0.f};

    #pragma unroll
    for (int kt = 0; kt < 4; kt++) {
        #pragma unroll
        for (int nt = 0; nt < 8; nt++) {
            bf16x8 whi, wlo;
            wfrag_lds(smw, kt * 8 + nt, lane, whi, wlo);
            MFMA3(acc[nt], whi, wlo, yh[kt], yl[kt]);
        }
    }

    if (arow < M) {
        float sc = rowScale[arow];
        #pragma unroll
        for (int nt = 0; nt < 8; nt++) {
            int cbase = 32 * (nt >> 1) + 8 * g + 4 * (nt & 1);
            uint4 o;
            o.x = pack_bf2(acc[nt][0] * sc);
            o.y = pack_bf2(acc[nt][1] * sc);
            o.z = pack_bf2(acc[nt][2] * sc);
            o.w = pack_bf2(acc[nt][3] * sc);
            *(uint4*)(Cout + (size_t)arow * 128 + cbase) = o;
        }
    }
}

// ---- fused predict MLP: gather xi/xj -> y1 -> y2 -> y3 -> dot -> out.
// 16 samples/wave; active weight matrix staged in LDS per layer (4 phases).
__global__ __launch_bounds__(512)
void mlp_k(const unsigned* __restrict__ X, const int* __restrict__ psrc, const int* __restrict__ pdst,
           const unsigned short* __restrict__ W1a, const unsigned short* __restrict__ W1b,
           const float* __restrict__ b1, const unsigned short* __restrict__ W2p,
           const float* __restrict__ b2, const unsigned short* __restrict__ W3p,
           const float* __restrict__ b3, const float* __restrict__ w4,
           const float* __restrict__ b4p, float* __restrict__ out, int M)
{
    __shared__ __align__(16) unsigned short smw[32768];   // 64 KB staging for active weights
    const int t = threadIdx.x, lane = t & 63, wave = t >> 6;
    const int base = blockIdx.x * 128 + wave * 16;
    const int s = lane & 15, g = lane >> 4, kg = g * 8;
    const int arow = base + s;
    const int rowc = (arow < M) ? arow : (M - 1);
    const int si = psrc[rowc], sj = pdst[rowc];

    f32x4 acc1[8];
    #pragma unroll
    for (int nt = 0; nt < 8; nt++) acc1[nt] = (f32x4){0.f, 0.f, 0.f, 0.f};

    // ---- phase 1a: stage W1a; preload xi frags under the staging latency ----
    stage_w(smw, W1a, t);
    {
        bf16x8 xh[4], xl[4];
        #pragma unroll
        for (int kt = 0; kt < 4; kt++)
            frag_from_packed(X + (size_t)si * 128 + kt * 32 + kg, xh[kt], xl[kt]);
        __syncthreads();
        #pragma unroll
        for (int kt = 0; kt < 4; kt++) {
            #pragma unroll
            for (int nt = 0; nt < 8; nt++) {
                bf16x8 whi, wlo;
                wfrag_lds(smw, kt * 8 + nt, lane, whi, wlo);
                MFMA3(acc1[nt], whi, wlo, xh[kt], xl[kt]);
            }
        }
    }
    __syncthreads();   // all reads of W1a done before overwrite

    // ---- phase 1b: stage W1b; preload xj frags ----
    stage_w(smw, W1b, t);
    {
        bf16x8 xh[4], xl[4];
        #pragma unroll
        for (int kt = 0; kt < 4; kt++)
            frag_from_packed(X + (size_t)sj * 128 + kt * 32 + kg, xh[kt], xl[kt]);
        __syncthreads();
        #pragma unroll
        for (int kt = 0; kt < 4; kt++) {
            #pragma unroll
            for (int nt = 0; nt < 8; nt++) {
                bf16x8 whi, wlo;
                wfrag_lds(smw, kt * 8 + nt, lane, whi, wlo);
                MFMA3(acc1[nt], whi, wlo, xh[kt], xl[kt]);
            }
        }
    }
    __syncthreads();

    // ---- layer 2 ----
    stage_w(smw, W2p, t);
    __syncthreads();
    f32x4 acc2[8];
    #pragma unroll
    for (int nt = 0; nt < 8; nt++) acc2[nt] = (f32x4){0.f, 0.f, 0.f, 0.f};
    #pragma unroll
    for (int kt = 0; kt < 4; kt++) {
        float4 bva = *(const float4*)(b1 + 32 * kt + 8 * g);
        float4 bvb = *(const float4*)(b1 + 32 * kt + 8 * g + 4);
        bf16x8 yh, yl;
        trans_frag(acc1, bva, bvb, kt, yh, yl);
        #pragma unroll
        for (int nt = 0; nt < 8; nt++) {
            bf16x8 whi, wlo;
            wfrag_lds(smw, kt * 8 + nt, lane, whi, wlo);
            MFMA3(acc2[nt], whi, wlo, yh, yl);
        }
    }
    __syncthreads();

    // ---- layer 3 ----
    stage_w(smw, W3p, t);
    __syncthreads();
    f32x4 acc3[8];
    #pragma unroll
    for (int nt = 0; nt < 8; nt++) acc3[nt] = (f32x4){0.f, 0.f, 0.f, 0.f};
    #pragma unroll
    for (int kt = 0; kt < 4; kt++) {
        float4 bva = *(const float4*)(b2 + 32 * kt + 8 * g);
        float4 bvb = *(const float4*)(b2 + 32 * kt + 8 * g + 4);
        bf16x8 yh, yl;
        trans_frag(acc2, bva, bvb, kt, yh, yl);
        #pragma unroll
        for (int nt = 0; nt < 8; nt++) {
            bf16x8 whi, wlo;
            wfrag_lds(smw, kt * 8 + nt, lane, whi, wlo);
            MFMA3(acc3[nt], whi, wlo, yh, yl);
        }
    }

    // ---- final: out = relu( sum_c relu(y3[c]) * w4[c] + b4 ) ----
    float p = 0.f;
    #pragma unroll
    for (int nt = 0; nt < 8; nt++) {
        int off = 32 * (nt >> 1) + 8 * g + 4 * (nt & 1);
        float4 b3v = *(const float4*)(b3 + off);
        float4 w4v = *(const float4*)(w4 + off);
        p += fmaxf(acc3[nt][0] + b3v.x, 0.f) * w4v.x;
        p += fmaxf(acc3[nt][1] + b3v.y, 0.f) * w4v.y;
        p += fmaxf(acc3[nt][2] + b3v.z, 0.f) * w4v.z;
        p += fmaxf(acc3[nt][3] + b3v.w, 0.f) * w4v.w;
    }
    p += __shfl_xor(p, 16, 64);
    p += __shfl_xor(p, 32, 64);
    if (g == 0 && arow < M) out[arow] = fmaxf(p + b4p[0], 0.f);
}

extern "C" void kernel_launch(void* const* d_in, const int* in_sizes, int n_in,
                              void* d_out, int out_size, void* d_ws, size_t ws_size,
                              hipStream_t stream)
{
    const float* x   = (const float*)d_in[0];
    const int*   ei  = (const int*)d_in[2];
    const int*   pei = (const int*)d_in[3];
    const float* W1  = (const float*)d_in[4];
    const float* b1  = (const float*)d_in[5];
    const float* W2  = (const float*)d_in[6];
    const float* b2  = (const float*)d_in[7];
    // d_in[8..11] = edge_mlp weights: dead w.r.t. output, skipped
    const float* pW1 = (const float*)d_in[12];
    const float* pb1 = (const float*)d_in[13];
    const float* pW2 = (const float*)d_in[14];
    const float* pb2 = (const float*)d_in[15];
    const float* pW3 = (const float*)d_in[16];
    const float* pb3 = (const float*)d_in[17];
    const float* pW4 = (const float*)d_in[18];
    const float* pb4 = (const float*)d_in[19];

    const int N  = in_sizes[0] / 128;
    const int E  = in_sizes[2] / 2;
    const int EP = in_sizes[3] / 2;
    const int Npad = (N + 255) & ~255;

    float*    ws     = (float*)d_ws;
    float*    dinv   = ws;                                  // Npad
    unsigned* bufA   = (unsigned*)(ws + Npad);              // N*128
    unsigned* bufB   = bufA + (size_t)N * 128;              // N*128
    int*      deg    = (int*)(bufB + (size_t)N * 128);      // Npad
    int*      rowptr = deg + Npad;                          // Npad
    int*      cursor = rowptr + Npad;                       // Npad
    int*      csr    = cursor + Npad;                       // E
    int*      bsum   = csr + E;                             // 512
    size_t wpOff = ((size_t)(bsum + 512) + 15) & ~(size_t)15;
    unsigned short* wp = (unsigned short*)wpOff;            // 6 x 32768 u16
    unsigned short* W1p  = wp;
    unsigned short* W2p  = wp + 32768;
    unsigned short* P1Ap = wp + 2 * 32768;
    unsigned short* P1Bp = wp + 3 * 32768;
    unsigned short* P2p  = wp + 4 * 32768;
    unsigned short* P3p  = wp + 5 * 32768;
    float* out = (float*)d_out;

    const int* esrc = ei;
    const int* edst = ei + E;
    const int* psrc = pei;
    const int* pdst = pei + EP;

    const int nb = (N + 255) / 256;
    const int gN = (N + 255) / 256;
    const int gE = (E + 255) / 256;
    const int gT = (N + 127) / 128;
    const int gP = (EP + 127) / 128;
    const int gG = (N + 15) / 16;

    // ---- CSR build + dinv ----
    zero2_k<<<gN, 256, 0, stream>>>(deg, cursor, N);
    hist_k<<<gE, 256, 0, stream>>>(edst, deg, E);
    scan1_k<<<nb, 256, 0, stream>>>(deg, rowptr, bsum, dinv, N);
    scan2_k<<<1, 512, 0, stream>>>(bsum, nb);
    scan3_k<<<gN, 256, 0, stream>>>(rowptr, bsum, N);
    place_k<<<gE, 256, 0, stream>>>(esrc, edst, rowptr, cursor, csr, E);

    // ---- weight prep ----
    wprep6_k<<<dim3(64, 6), 256, 0, stream>>>(W1, W2, pW1, pW1 + 128 * 128, pW2, pW3, wp);

    // ---- layer 0: hp1 = dinv ⊙ (x@W1); x1r = relu(agg + b1) ----
    rowgemm_k<0><<<gT, 512, 0, stream>>>(x, W1p, dinv, bufA, N);
    gather4_k<<<gG, 256, 0, stream>>>(bufA, dinv, rowptr, deg, csr, b1, bufB, N);

    // ---- layer 1 ----
    rowgemm_k<1><<<gT, 512, 0, stream>>>(bufB, W2p, dinv, bufA, N);
    gather4_k<<<gG, 256, 0, stream>>>(bufA, dinv, rowptr, deg, csr, b2, bufB, N);

    // ---- fused predict MLP ----
    mlp_k<<<gP, 512, 0, stream>>>(bufB, psrc, pdst, P1Ap, P1Bp, pb1, P2p, pb2, P3p, pb3,
                                  pW4, pb4, out, EP);
}

// Round 8
// 244.621 us; speedup vs baseline: 1.4983x; 1.2334x over previous
//
#include <hip/hip_runtime.h>

typedef __attribute__((ext_vector_type(8))) short bf16x8;
typedef __attribute__((ext_vector_type(4))) float f32x4;

// ---- split-bf16 helpers: value v ~ hi + lo, packed as (hi16<<16)|lo16 ----
__device__ __forceinline__ unsigned bfr16(float x) {            // RNE fp32->bf16 bits
    unsigned u = __float_as_uint(x);
    return (u + 0x7fffu + ((u >> 16) & 1u)) >> 16;
}
__device__ __forceinline__ unsigned pack_bf2(float v) {
    unsigned hr = bfr16(v);
    float lof = v - __uint_as_float(hr << 16);
    unsigned lr = bfr16(lof);
    return (hr << 16) | (lr & 0xffffu);
}
__device__ __forceinline__ float dec_bf2(unsigned p) {
    return __uint_as_float(p & 0xffff0000u) + __uint_as_float(p << 16);
}
// bf16 pair decode (two ushorts in one u32)
__device__ __forceinline__ float lo16f(unsigned u) { return __uint_as_float(u << 16); }
__device__ __forceinline__ float hi16f(unsigned u) { return __uint_as_float(u & 0xffff0000u); }

union U8 { bf16x8 v; unsigned u[4]; };

// activation B-fragment from 8 consecutive packed u32 (sample = lane&15, k-slice = (lane>>4)*8)
__device__ __forceinline__ void frag_from_packed(const unsigned* ap, bf16x8& hi, bf16x8& lo) {
    uint4 u0 = *(const uint4*)ap;
    uint4 u1 = *(const uint4*)(ap + 4);
    U8 H, L;
    H.u[0] = __builtin_amdgcn_perm(u0.y, u0.x, 0x07060302u);
    H.u[1] = __builtin_amdgcn_perm(u0.w, u0.z, 0x07060302u);
    H.u[2] = __builtin_amdgcn_perm(u1.y, u1.x, 0x07060302u);
    H.u[3] = __builtin_amdgcn_perm(u1.w, u1.z, 0x07060302u);
    L.u[0] = __builtin_amdgcn_perm(u0.y, u0.x, 0x05040100u);
    L.u[1] = __builtin_amdgcn_perm(u0.w, u0.z, 0x05040100u);
    L.u[2] = __builtin_amdgcn_perm(u1.y, u1.x, 0x05040100u);
    L.u[3] = __builtin_amdgcn_perm(u1.w, u1.z, 0x05040100u);
    hi = H.v; lo = L.v;
}

__device__ __forceinline__ void frag_from_f32(const float* fp, bf16x8& hi, bf16x8& lo) {
    float4 f0 = *(const float4*)fp;
    float4 f1 = *(const float4*)(fp + 4);
    float fv[8] = {f0.x, f0.y, f0.z, f0.w, f1.x, f1.y, f1.z, f1.w};
    U8 H, L;
    #pragma unroll
    for (int p = 0; p < 4; p++) {
        float a = fv[2 * p], b = fv[2 * p + 1];
        unsigned ra = bfr16(a), rb = bfr16(b);
        H.u[p] = ra | (rb << 16);
        float la = a - __uint_as_float(ra << 16);
        float lb = b - __uint_as_float(rb << 16);
        L.u[p] = bfr16(la) | (bfr16(lb) << 16);
    }
    hi = H.v; lo = L.v;
}

// stage one prepped weight matrix (64 KB: hi plane 32 KB + lo plane 32 KB) into LDS
__device__ __forceinline__ void stage_w(unsigned short* sm, const unsigned short* Wp, int t) {
    const uint4* src = (const uint4*)Wp;
    uint4* dst = (uint4*)sm;
    #pragma unroll
    for (int p = 0; p < 8; p++) dst[t + p * 512] = src[t + p * 512];
}

// weight A-operand fragment pair from LDS (hi at 0, lo at +16384 u16)
__device__ __forceinline__ void wfrag_lds(const unsigned short* sm, int f, int lane,
                                          bf16x8& whi, bf16x8& wlo) {
    whi = *(const bf16x8*)(sm + f * 512 + lane * 8);
    wlo = *(const bf16x8*)(sm + 16384 + f * 512 + lane * 8);
}

#define MFMA3(accv, whi, wlo, yhi, ylo)                                              \
    accv = __builtin_amdgcn_mfma_f32_16x16x32_bf16(whi, yhi, accv, 0, 0, 0);         \
    accv = __builtin_amdgcn_mfma_f32_16x16x32_bf16(whi, ylo, accv, 0, 0, 0);         \
    accv = __builtin_amdgcn_mfma_f32_16x16x32_bf16(wlo, yhi, accv, 0, 0, 0);

// slot->true-channel map: chan(nt, rho=4g+r) = 32*(nt>>1) + 8*g + 4*(nt&1) + r
// self-consistent: B-frag built as acc[2kt+(j>>2)][j&3] reads true channel kt*32+g*8+j.

// layer transition entirely in registers: y(kt) fragment from acc + bias (+relu)
__device__ __forceinline__ void trans_frag(const f32x4* acc, float4 bva, float4 bvb, int kt,
                                           bf16x8& yh, bf16x8& yl) {
    const int n0 = 2 * kt, n1 = n0 + 1;
    float v0 = fmaxf(acc[n0][0] + bva.x, 0.f);
    float v1 = fmaxf(acc[n0][1] + bva.y, 0.f);
    float v2 = fmaxf(acc[n0][2] + bva.z, 0.f);
    float v3 = fmaxf(acc[n0][3] + bva.w, 0.f);
    float v4 = fmaxf(acc[n1][0] + bvb.x, 0.f);
    float v5 = fmaxf(acc[n1][1] + bvb.y, 0.f);
    float v6 = fmaxf(acc[n1][2] + bvb.z, 0.f);
    float v7 = fmaxf(acc[n1][3] + bvb.w, 0.f);
    U8 H, L;
    unsigned ra, rb;
    ra = bfr16(v0); rb = bfr16(v1);
    H.u[0] = ra | (rb << 16);
    L.u[0] = bfr16(v0 - __uint_as_float(ra << 16)) | (bfr16(v1 - __uint_as_float(rb << 16)) << 16);
    ra = bfr16(v2); rb = bfr16(v3);
    H.u[1] = ra | (rb << 16);
    L.u[1] = bfr16(v2 - __uint_as_float(ra << 16)) | (bfr16(v3 - __uint_as_float(rb << 16)) << 16);
    ra = bfr16(v4); rb = bfr16(v5);
    H.u[2] = ra | (rb << 16);
    L.u[2] = bfr16(v4 - __uint_as_float(ra << 16)) | (bfr16(v5 - __uint_as_float(rb << 16)) << 16);
    ra = bfr16(v6); rb = bfr16(v7);
    H.u[3] = ra | (rb << 16);
    L.u[3] = bfr16(v6 - __uint_as_float(ra << 16)) | (bfr16(v7 - __uint_as_float(rb << 16)) << 16);
    yh = H.v; yl = L.v;
}

// ---------------- CSR build ----------------

__global__ void zero2_k(int* __restrict__ a, int* __restrict__ b, int n) {
    int i = blockIdx.x * blockDim.x + threadIdx.x;
    if (i < n) { a[i] = 0; b[i] = 0; }
}

__global__ void hist_k(const int* __restrict__ dst, int* __restrict__ deg, int E) {
    int e = blockIdx.x * blockDim.x + threadIdx.x;
    if (e < E) atomicAdd(&deg[dst[e]], 1);
}

__global__ void scan1_k(const int* __restrict__ deg, int* __restrict__ rowptr,
                        int* __restrict__ bsum, float* __restrict__ dinv, int n) {
    __shared__ int s[256];
    int tid = threadIdx.x;
    int i = blockIdx.x * 256 + tid;
    int v = (i < n) ? deg[i] : 0;
    s[tid] = v;
    __syncthreads();
    #pragma unroll
    for (int off = 1; off < 256; off <<= 1) {
        int t = (tid >= off) ? s[tid - off] : 0;
        __syncthreads();
        s[tid] += t;
        __syncthreads();
    }
    if (i < n) {
        rowptr[i] = s[tid] - v;
        dinv[i] = rsqrtf((float)(v + 1));
    }
    if (tid == 255) bsum[blockIdx.x] = s[255];
}

__global__ void scan2_k(int* __restrict__ bsum, int nb) {
    __shared__ int s[512];
    int tid = threadIdx.x;
    int v = (tid < nb) ? bsum[tid] : 0;
    s[tid] = v;
    __syncthreads();
    #pragma unroll
    for (int off = 1; off < 512; off <<= 1) {
        int t = (tid >= off) ? s[tid - off] : 0;
        __syncthreads();
        s[tid] += t;
        __syncthreads();
    }
    if (tid < nb) bsum[tid] = s[tid] - v;
}

__global__ void scan3_k(int* __restrict__ rowptr, const int* __restrict__ bsum, int n) {
    int i = blockIdx.x * blockDim.x + threadIdx.x;
    if (i < n) rowptr[i] += bsum[i >> 8];
}

__global__ void place_k(const int* __restrict__ src, const int* __restrict__ dst,
                        const int* __restrict__ rowptr, int* __restrict__ cursor,
                        int* __restrict__ csr, int E) {
    int e = blockIdx.x * blockDim.x + threadIdx.x;
    if (e < E) {
        int d = dst[e];
        int pos = rowptr[d] + atomicAdd(&cursor[d], 1);
        csr[pos] = src[e];
    }
}

// ---- weight prep: W[k][c] -> A-operand frag (slot-permuted columns) ----
__global__ void wprep6_k(const float* __restrict__ s0, const float* __restrict__ s1,
                         const float* __restrict__ s2, const float* __restrict__ s3,
                         const float* __restrict__ s4, const float* __restrict__ s5,
                         unsigned short* __restrict__ dstBase) {
    const float* W;
    switch (blockIdx.y) {
        case 0: W = s0; break; case 1: W = s1; break; case 2: W = s2; break;
        case 3: W = s3; break; case 4: W = s4; break; default: W = s5; break;
    }
    unsigned short* out = dstBase + (size_t)blockIdx.y * 32768;
    int idx = blockIdx.x * 256 + threadIdx.x;
    if (idx >= 16384) return;
    int k = idx >> 7, c = idx & 127;
    float v = W[k * 128 + c];
    unsigned hr = bfr16(v);
    float lof = v - __uint_as_float(hr << 16);
    unsigned lr = bfr16(lof);
    int kt = k >> 5, gk = (k >> 3) & 3, j = k & 7;
    int nt = ((c >> 5) << 1) | ((c >> 2) & 1);
    int rho = (((c >> 3) & 3) << 2) | (c & 3);
    int lane = (gk << 4) | rho;
    int pos = (kt * 8 + nt) * 512 + lane * 8 + j;
    out[pos] = (unsigned short)hr;
    out[16384 + pos] = (unsigned short)lr;
}

// ---- gather aggregate: out[i] = relu(bias + dinv[i]*(hp[i] + sum_in hp[s])).
// hp is a bf16 hi-plane (2 B/chan): neighbor row = 256 B. 4 nodes/wave,
// 16 lanes x 8 channels (one uint4 = 8 bf16) per node; 4-way unrolled loop.
// Output packed split-bf16.
__global__ __launch_bounds__(256)
void gather4_k(const unsigned short* __restrict__ hp, const float* __restrict__ dinv,
               const int* __restrict__ rowptr, const int* __restrict__ deg,
               const int* __restrict__ csr, const float* __restrict__ bias,
               unsigned* __restrict__ out, int N)
{
    int tid = threadIdx.x;
    int lane = tid & 63;
    int grp = lane >> 4, cl = lane & 15;
    int i = blockIdx.x * 16 + (tid >> 6) * 4 + grp;
    if (i >= N) return;
    int c8 = cl * 8;
    uint4 p = *(const uint4*)(hp + (size_t)i * 128 + c8);
    float a0 = lo16f(p.x), a1 = hi16f(p.x), a2 = lo16f(p.y), a3 = hi16f(p.y);
    float a4 = lo16f(p.z), a5 = hi16f(p.z), a6 = lo16f(p.w), a7 = hi16f(p.w);
    int beg = rowptr[i], dg = deg[i];
    int j = 0;
    for (; j + 3 < dg; j += 4) {
        int s0 = csr[beg + j],     s1 = csr[beg + j + 1];
        int s2 = csr[beg + j + 2], s3 = csr[beg + j + 3];
        uint4 q0 = *(const uint4*)(hp + (size_t)s0 * 128 + c8);
        uint4 q1 = *(const uint4*)(hp + (size_t)s1 * 128 + c8);
        uint4 q2 = *(const uint4*)(hp + (size_t)s2 * 128 + c8);
        uint4 q3 = *(const uint4*)(hp + (size_t)s3 * 128 + c8);
        a0 += (lo16f(q0.x) + lo16f(q1.x)) + (lo16f(q2.x) + lo16f(q3.x));
        a1 += (hi16f(q0.x) + hi16f(q1.x)) + (hi16f(q2.x) + hi16f(q3.x));
        a2 += (lo16f(q0.y) + lo16f(q1.y)) + (lo16f(q2.y) + lo16f(q3.y));
        a3 += (hi16f(q0.y) + hi16f(q1.y)) + (hi16f(q2.y) + hi16f(q3.y));
        a4 += (lo16f(q0.z) + lo16f(q1.z)) + (lo16f(q2.z) + lo16f(q3.z));
        a5 += (hi16f(q0.z) + hi16f(q1.z)) + (hi16f(q2.z) + hi16f(q3.z));
        a6 += (lo16f(q0.w) + lo16f(q1.w)) + (lo16f(q2.w) + lo16f(q3.w));
        a7 += (hi16f(q0.w) + hi16f(q1.w)) + (hi16f(q2.w) + hi16f(q3.w));
    }
    for (; j < dg; j++) {
        int s0 = csr[beg + j];
        uint4 q0 = *(const uint4*)(hp + (size_t)s0 * 128 + c8);
        a0 += lo16f(q0.x); a1 += hi16f(q0.x); a2 += lo16f(q0.y); a3 += hi16f(q0.y);
        a4 += lo16f(q0.z); a5 += hi16f(q0.z); a6 += lo16f(q0.w); a7 += hi16f(q0.w);
    }
    float di = dinv[i];
    float4 bv0 = *(const float4*)(bias + c8);
    float4 bv1 = *(const float4*)(bias + c8 + 4);
    uint4 o0, o1;
    o0.x = pack_bf2(fmaxf(bv0.x + di * a0, 0.f));
    o0.y = pack_bf2(fmaxf(bv0.y + di * a1, 0.f));
    o0.z = pack_bf2(fmaxf(bv0.z + di * a2, 0.f));
    o0.w = pack_bf2(fmaxf(bv0.w + di * a3, 0.f));
    o1.x = pack_bf2(fmaxf(bv1.x + di * a4, 0.f));
    o1.y = pack_bf2(fmaxf(bv1.y + di * a5, 0.f));
    o1.z = pack_bf2(fmaxf(bv1.z + di * a6, 0.f));
    o1.w = pack_bf2(fmaxf(bv1.w + di * a7, 0.f));
    *(uint4*)(out + (size_t)i * 128 + c8) = o0;
    *(uint4*)(out + (size_t)i * 128 + c8 + 4) = o1;
}

// ---- layer GEMM: Chp = dinv-row-scaled (A @ W) as bf16 hi-plane. 16 rows/wave, W in LDS. ----
template<int AMODE>   // 0: A fp32 ; 1: A packed split-bf16
__global__ __launch_bounds__(512)
void rowgemm_k(const void* __restrict__ Asrc, const unsigned short* __restrict__ Wp,
               const float* __restrict__ rowScale, unsigned short* __restrict__ CoutHi, int M)
{
    __shared__ __align__(16) unsigned short smw[32768];   // 64 KB: one prepped weight matrix
    const int t = threadIdx.x, lane = t & 63, wave = t >> 6;
    const int base = blockIdx.x * 128 + wave * 16;
    const int s = lane & 15, g = lane >> 4, kg = g * 8;
    const int arow = base + s;
    const int rowc = (arow < M) ? arow : (M - 1);

    stage_w(smw, Wp, t);

    // load A fragments while the staging lands
    bf16x8 yh[4], yl[4];
    #pragma unroll
    for (int kt = 0; kt < 4; kt++) {
        if (AMODE == 1)
            frag_from_packed((const unsigned*)Asrc + (size_t)rowc * 128 + kt * 32 + kg, yh[kt], yl[kt]);
        else
            frag_from_f32((const float*)Asrc + (size_t)rowc * 128 + kt * 32 + kg, yh[kt], yl[kt]);
    }
    __syncthreads();

    f32x4 acc[8];
    #pragma unroll
    for (int nt = 0; nt < 8; nt++) acc[nt] = (f32x4){0.f, 0.f, 0.f, 0.f};

    #pragma unroll
    for (int kt = 0; kt < 4; kt++) {
        #pragma unroll
        for (int nt = 0; nt < 8; nt++) {
            bf16x8 whi, wlo;
            wfrag_lds(smw, kt * 8 + nt, lane, whi, wlo);
            MFMA3(acc[nt], whi, wlo, yh[kt], yl[kt]);
        }
    }

    if (arow < M) {
        float sc = rowScale[arow];
        #pragma unroll
        for (int nt = 0; nt < 8; nt++) {
            int cbase = 32 * (nt >> 1) + 8 * g + 4 * (nt & 1);
            ushort4 o;
            o.x = (unsigned short)bfr16(acc[nt][0] * sc);
            o.y = (unsigned short)bfr16(acc[nt][1] * sc);
            o.z = (unsigned short)bfr16(acc[nt][2] * sc);
            o.w = (unsigned short)bfr16(acc[nt][3] * sc);
            *(ushort4*)(CoutHi + (size_t)arow * 128 + cbase) = o;
        }
    }
}

// ---- fused predict MLP: gather xi/xj -> y1 -> y2 -> y3 -> dot -> out.
// 16 samples/wave; active weight matrix staged in LDS per layer (4 phases).
__global__ __launch_bounds__(512)
void mlp_k(const unsigned* __restrict__ X, const int* __restrict__ psrc, const int* __restrict__ pdst,
           const unsigned short* __restrict__ W1a, const unsigned short* __restrict__ W1b,
           const float* __restrict__ b1, const unsigned short* __restrict__ W2p,
           const float* __restrict__ b2, const unsigned short* __restrict__ W3p,
           const float* __restrict__ b3, const float* __restrict__ w4,
           const float* __restrict__ b4p, float* __restrict__ out, int M)
{
    __shared__ __align__(16) unsigned short smw[32768];   // 64 KB staging for active weights
    const int t = threadIdx.x, lane = t & 63, wave = t >> 6;
    const int base = blockIdx.x * 128 + wave * 16;
    const int s = lane & 15, g = lane >> 4, kg = g * 8;
    const int arow = base + s;
    const int rowc = (arow < M) ? arow : (M - 1);
    const int si = psrc[rowc], sj = pdst[rowc];

    f32x4 acc1[8];
    #pragma unroll
    for (int nt = 0; nt < 8; nt++) acc1[nt] = (f32x4){0.f, 0.f, 0.f, 0.f};

    // ---- phase 1a: stage W1a; preload xi frags under the staging latency ----
    stage_w(smw, W1a, t);
    {
        bf16x8 xh[4], xl[4];
        #pragma unroll
        for (int kt = 0; kt < 4; kt++)
            frag_from_packed(X + (size_t)si * 128 + kt * 32 + kg, xh[kt], xl[kt]);
        __syncthreads();
        #pragma unroll
        for (int kt = 0; kt < 4; kt++) {
            #pragma unroll
            for (int nt = 0; nt < 8; nt++) {
                bf16x8 whi, wlo;
                wfrag_lds(smw, kt * 8 + nt, lane, whi, wlo);
                MFMA3(acc1[nt], whi, wlo, xh[kt], xl[kt]);
            }
        }
    }
    __syncthreads();   // all reads of W1a done before overwrite

    // ---- phase 1b: stage W1b; preload xj frags ----
    stage_w(smw, W1b, t);
    {
        bf16x8 xh[4], xl[4];
        #pragma unroll
        for (int kt = 0; kt < 4; kt++)
            frag_from_packed(X + (size_t)sj * 128 + kt * 32 + kg, xh[kt], xl[kt]);
        __syncthreads();
        #pragma unroll
        for (int kt = 0; kt < 4; kt++) {
            #pragma unroll
            for (int nt = 0; nt < 8; nt++) {
                bf16x8 whi, wlo;
                wfrag_lds(smw, kt * 8 + nt, lane, whi, wlo);
                MFMA3(acc1[nt], whi, wlo, xh[kt], xl[kt]);
            }
        }
    }
    __syncthreads();

    // ---- layer 2 ----
    stage_w(smw, W2p, t);
    __syncthreads();
    f32x4 acc2[8];
    #pragma unroll
    for (int nt = 0; nt < 8; nt++) acc2[nt] = (f32x4){0.f, 0.f, 0.f, 0.f};
    #pragma unroll
    for (int kt = 0; kt < 4; kt++) {
        float4 bva = *(const float4*)(b1 + 32 * kt + 8 * g);
        float4 bvb = *(const float4*)(b1 + 32 * kt + 8 * g + 4);
        bf16x8 yh, yl;
        trans_frag(acc1, bva, bvb, kt, yh, yl);
        #pragma unroll
        for (int nt = 0; nt < 8; nt++) {
            bf16x8 whi, wlo;
            wfrag_lds(smw, kt * 8 + nt, lane, whi, wlo);
            MFMA3(acc2[nt], whi, wlo, yh, yl);
        }
    }
    __syncthreads();

    // ---- layer 3 ----
    stage_w(smw, W3p, t);
    __syncthreads();
    f32x4 acc3[8];
    #pragma unroll
    for (int nt = 0; nt < 8; nt++) acc3[nt] = (f32x4){0.f, 0.f, 0.f, 0.f};
    #pragma unroll
    for (int kt = 0; kt < 4; kt++) {
        float4 bva = *(const float4*)(b2 + 32 * kt + 8 * g);
        float4 bvb = *(const float4*)(b2 + 32 * kt + 8 * g + 4);
        bf16x8 yh, yl;
        trans_frag(acc2, bva, bvb, kt, yh, yl);
        #pragma unroll
        for (int nt = 0; nt < 8; nt++) {
            bf16x8 whi, wlo;
            wfrag_lds(smw, kt * 8 + nt, lane, whi, wlo);
            MFMA3(acc3[nt], whi, wlo, yh, yl);
        }
    }

    // ---- final: out = relu( sum_c relu(y3[c]) * w4[c] + b4 ) ----
    float p = 0.f;
    #pragma unroll
    for (int nt = 0; nt < 8; nt++) {
        int off = 32 * (nt >> 1) + 8 * g + 4 * (nt & 1);
        float4 b3v = *(const float4*)(b3 + off);
        float4 w4v = *(const float4*)(w4 + off);
        p += fmaxf(acc3[nt][0] + b3v.x, 0.f) * w4v.x;
        p += fmaxf(acc3[nt][1] + b3v.y, 0.f) * w4v.y;
        p += fmaxf(acc3[nt][2] + b3v.z, 0.f) * w4v.z;
        p += fmaxf(acc3[nt][3] + b3v.w, 0.f) * w4v.w;
    }
    p += __shfl_xor(p, 16, 64);
    p += __shfl_xor(p, 32, 64);
    if (g == 0 && arow < M) out[arow] = fmaxf(p + b4p[0], 0.f);
}

extern "C" void kernel_launch(void* const* d_in, const int* in_sizes, int n_in,
                              void* d_out, int out_size, void* d_ws, size_t ws_size,
                              hipStream_t stream)
{
    const float* x   = (const float*)d_in[0];
    const int*   ei  = (const int*)d_in[2];
    const int*   pei = (const int*)d_in[3];
    const float* W1  = (const float*)d_in[4];
    const float* b1  = (const float*)d_in[5];
    const float* W2  = (const float*)d_in[6];
    const float* b2  = (const float*)d_in[7];
    // d_in[8..11] = edge_mlp weights: dead w.r.t. output, skipped
    const float* pW1 = (const float*)d_in[12];
    const float* pb1 = (const float*)d_in[13];
    const float* pW2 = (const float*)d_in[14];
    const float* pb2 = (const float*)d_in[15];
    const float* pW3 = (const float*)d_in[16];
    const float* pb3 = (const float*)d_in[17];
    const float* pW4 = (const float*)d_in[18];
    const float* pb4 = (const float*)d_in[19];

    const int N  = in_sizes[0] / 128;
    const int E  = in_sizes[2] / 2;
    const int EP = in_sizes[3] / 2;
    const int Npad = (N + 255) & ~255;

    float*    ws     = (float*)d_ws;
    float*    dinv   = ws;                                  // Npad
    unsigned* bufA   = (unsigned*)(ws + Npad);              // N*128 u32 region (hp uses half as bf16 plane)
    unsigned* bufB   = bufA + (size_t)N * 128;              // N*128 packed split-bf16
    int*      deg    = (int*)(bufB + (size_t)N * 128);      // Npad
    int*      rowptr = deg + Npad;                          // Npad
    int*      cursor = rowptr + Npad;                       // Npad
    int*      csr    = cursor + Npad;                       // E
    int*      bsum   = csr + E;                             // 512
    size_t wpOff = ((size_t)(bsum + 512) + 15) & ~(size_t)15;
    unsigned short* wp = (unsigned short*)wpOff;            // 6 x 32768 u16
    unsigned short* W1p  = wp;
    unsigned short* W2p  = wp + 32768;
    unsigned short* P1Ap = wp + 2 * 32768;
    unsigned short* P1Bp = wp + 3 * 32768;
    unsigned short* P2p  = wp + 4 * 32768;
    unsigned short* P3p  = wp + 5 * 32768;
    unsigned short* hpHi = (unsigned short*)bufA;           // bf16 hi-plane, N*128 u16
    float* out = (float*)d_out;

    const int* esrc = ei;
    const int* edst = ei + E;
    const int* psrc = pei;
    const int* pdst = pei + EP;

    const int nb = (N + 255) / 256;
    const int gN = (N + 255) / 256;
    const int gE = (E + 255) / 256;
    const int gT = (N + 127) / 128;
    const int gP = (EP + 127) / 128;
    const int gG = (N + 15) / 16;

    // ---- CSR build + dinv ----
    zero2_k<<<gN, 256, 0, stream>>>(deg, cursor, N);
    hist_k<<<gE, 256, 0, stream>>>(edst, deg, E);
    scan1_k<<<nb, 256, 0, stream>>>(deg, rowptr, bsum, dinv, N);
    scan2_k<<<1, 512, 0, stream>>>(bsum, nb);
    scan3_k<<<gN, 256, 0, stream>>>(rowptr, bsum, N);
    place_k<<<gE, 256, 0, stream>>>(esrc, edst, rowptr, cursor, csr, E);

    // ---- weight prep ----
    wprep6_k<<<dim3(64, 6), 256, 0, stream>>>(W1, W2, pW1, pW1 + 128 * 128, pW2, pW3, wp);

    // ---- layer 0: hp1 = dinv ⊙ (x@W1) [bf16 hi-plane]; x1r = relu(agg + b1) [packed] ----
    rowgemm_k<0><<<gT, 512, 0, stream>>>(x, W1p, dinv, hpHi, N);
    gather4_k<<<gG, 256, 0, stream>>>(hpHi, dinv, rowptr, deg, csr, b1, bufB, N);

    // ---- layer 1 ----
    rowgemm_k<1><<<gT, 512, 0, stream>>>(bufB, W2p, dinv, hpHi, N);
    gather4_k<<<gG, 256, 0, stream>>>(hpHi, dinv, rowptr, deg, csr, b2, bufB, N);

    // ---- fused predict MLP ----
    mlp_k<<<gP, 512, 0, stream>>>(bufB, psrc, pdst, P1Ap, P1Bp, pb1, P2p, pb2, P3p, pb3,
                                  pW4, pb4, out, EP);
}